// Round 7
// baseline (124.976 us; speedup 1.0000x reference)
//
#include <hip/hip_runtime.h>

// DCNv3 forward, fp32 in/out. Layouts (from the reference's view-reshapes):
//   x   : (B=4, H=128, W=128, C=128) flat — idx = ((b*128+h)*128+w)*128+c
//   out : same
//   W_off (128,72), b_off(72), W_mask(128,36), b_mask(36)
// Tier-1 ws layout:
//   [0)            x16 : bf16 copy of x, GROUP-PLANAR (16 MB):
//                  x16[((g*4+b)*16384 + y*128 + x)*32 + ch], ch in [0,32)
//   [NPIX*128*2)   ws16: fp16 SoA planes (14.2 MB): ws16[j*NPIX + pix]
//                  j<72 = offsets (g,p,2); j in [72,108) = mask LOGITS
//                  (softmax done in samp).

#define NPIX 65536  // B*H*W

typedef unsigned int uint;
typedef unsigned short ushort;
typedef __attribute__((ext_vector_type(8))) short short8v;   // 8 bf16
typedef __attribute__((ext_vector_type(4))) float f32x4;

__device__ __forceinline__ ushort f2bf(float f) {
  uint u = __float_as_uint(f);
  u += 0x7FFFu + ((u >> 16) & 1u);  // RNE
  return (ushort)(u >> 16);
}
__device__ __forceinline__ uint pkbf(float lo, float hi) {
  return (uint)f2bf(lo) | ((uint)f2bf(hi) << 16);
}
__device__ __forceinline__ float bflo(uint d) { return __uint_as_float(d << 16); }
__device__ __forceinline__ float bfhi(uint d) { return __uint_as_float(d & 0xFFFF0000u); }
__device__ __forceinline__ ushort f2h(float f) {
  union { _Float16 h; ushort u; } cv;
  cv.h = (_Float16)f;
  return cv.u;
}
__device__ __forceinline__ float h2f(ushort u) {
  union { ushort u; _Float16 h; } cv;
  cv.u = u;
  return (float)cv.h;
}

union U8 { uint u[4]; short8v v; };

// ---------------- Kernel A: MFMA linear layers + fused bf16 pack -----------
// grid 1024, block 256 (4 waves). Wave = 16 pixels x 112 cols (7 N-tiles),
// K=128 (4 k-tiles of 32). W^T staged in LDS as bf16 pairs, stride 68 u32.
// C/D layout (m89-verified): col=lane&15 (output col n), row=(lane>>4)*4+reg
// (pixel) -> acc[nt] is 4 consecutive pixels of one ws plane -> ushort4 store.
__global__ __launch_bounds__(256) void dcn_lin_mfma(
    const float* __restrict__ x, const float* __restrict__ Woff,
    const float* __restrict__ boff, const float* __restrict__ Wmask,
    const float* __restrict__ bmask, ushort* __restrict__ ws16,
    ushort* __restrict__ x16) {
  __shared__ uint wt[112 * 68];
  __shared__ float bias_lds[112];
  const int pbase = blockIdx.x << 6;  // 64 pixels per block
  const int t = threadIdx.x;

  // ---- stage W^T (bf16 k-pairs) into LDS: wt[n*68 + k/2] ----
  {
    int n = t, row = 0;
    bool act = true;
    if (t >= 224) act = false;
    else if (t >= 112) { n = t - 112; row = 1; }
    if (act) {
      for (int kp = row; kp < 64; kp += 2) {
        const int k = kp << 1;
        float w0, w1;
        if (n < 72) {
          w0 = Woff[k * 72 + n];        w1 = Woff[k * 72 + 72 + n];
        } else if (n < 108) {
          w0 = Wmask[k * 36 + n - 72];  w1 = Wmask[k * 36 + 36 + n - 72];
        } else {
          w0 = 0.f; w1 = 0.f;
        }
        wt[n * 68 + kp] = pkbf(w0, w1);
      }
    }
    if (t < 112)
      bias_lds[t] = (t < 72) ? boff[t] : (t < 108 ? bmask[t - 72] : 0.f);
  }

  // ---- fused bf16 group-planar pack (no LDS dependency) ----
  if (x16) {
    const int pix2 = pbase + (t >> 2);
    const int quad = t & 3;  // = group
    const float* xp = x + (size_t)pix2 * 128 + (quad << 5);
    const int bb = pix2 >> 14, yx = pix2 & 16383;
    ushort* dst = x16 + ((((size_t)((quad << 2) | bb) << 14) | yx) << 5);
#pragma unroll
    for (int ck = 0; ck < 2; ++ck) {
      const float4 a = *(const float4*)(xp + ck * 16);
      const float4 b4 = *(const float4*)(xp + ck * 16 + 4);
      const float4 c4 = *(const float4*)(xp + ck * 16 + 8);
      const float4 d4 = *(const float4*)(xp + ck * 16 + 12);
      uint4 s0, s1;
      s0.x = pkbf(a.x, a.y);   s0.y = pkbf(a.z, a.w);
      s0.z = pkbf(b4.x, b4.y); s0.w = pkbf(b4.z, b4.w);
      s1.x = pkbf(c4.x, c4.y); s1.y = pkbf(c4.z, c4.w);
      s1.z = pkbf(d4.x, d4.y); s1.w = pkbf(d4.z, d4.w);
      *(uint4*)(dst + ck * 16) = s0;
      *(uint4*)(dst + ck * 16 + 8) = s1;
    }
  }
  __syncthreads();

  // ---- MFMA ----
  const int wv = t >> 6;
  const int lane = t & 63;
  const int lrow = lane & 15;  // A-row (pixel) / B-col (n)
  const int lhi = lane >> 4;   // k sub-block
  const int pixrow = pbase + (wv << 4) + lrow;

  U8 afr[4];
#pragma unroll
  for (int kt = 0; kt < 4; ++kt) {
    const float* ax = x + (size_t)pixrow * 128 + (kt << 5) + (lhi << 3);
    const float4 xa = *(const float4*)ax;
    const float4 xb4 = *(const float4*)(ax + 4);
    afr[kt].u[0] = pkbf(xa.x, xa.y);   afr[kt].u[1] = pkbf(xa.z, xa.w);
    afr[kt].u[2] = pkbf(xb4.x, xb4.y); afr[kt].u[3] = pkbf(xb4.z, xb4.w);
  }

  f32x4 acc[7];
#pragma unroll
  for (int nt = 0; nt < 7; ++nt) {
    const float bv = bias_lds[(nt << 4) + lrow];
    f32x4 a4 = {bv, bv, bv, bv};
#pragma unroll
    for (int kt = 0; kt < 4; ++kt) {
      U8 bfr;
      const uint4 bw =
          *(const uint4*)(wt + ((nt << 4) + lrow) * 68 + (kt << 4) + (lhi << 2));
      bfr.u[0] = bw.x; bfr.u[1] = bw.y; bfr.u[2] = bw.z; bfr.u[3] = bw.w;
      a4 = __builtin_amdgcn_mfma_f32_16x16x32_bf16(afr[kt].v, bfr.v, a4, 0, 0, 0);
    }
    acc[nt] = a4;
  }

  // ---- epilogue: fp16 ushort4 stores into SoA ws16 ----
  const int rowb = pbase + (wv << 4) + (lhi << 2);
#pragma unroll
  for (int nt = 0; nt < 7; ++nt) {
    const int n = (nt << 4) + lrow;
    if (n < 108) {
      ushort4 hv;
      hv.x = f2h(acc[nt].x);
      hv.y = f2h(acc[nt].y);
      hv.z = f2h(acc[nt].z);
      hv.w = f2h(acc[nt].w);
      *(ushort4*)(ws16 + (size_t)n * NPIX + rowb) = hv;
    }
  }
}

// ---------------- Kernel B: bilinear gather from bf16 planar ---------------
// block 256 = (16x4 pixel tile) x 4 chunk-lanes; g = blockIdx&3.
// Gather footprint/block ~ 13x25 lines ~ 21KB -> L1-resident.
// 9 points processed in 3 batches of 3: 12 uint4 loads issued back-to-back
// per batch for memory-level parallelism.
__global__ __launch_bounds__(256, 4) void dcn_samp(
    const ushort* __restrict__ x16, const ushort* __restrict__ ws16,
    float* __restrict__ out) {
  const int g = blockIdx.x & 3;
  const int tile = blockIdx.x >> 2;       // b(2) : ty(5) : tx(3)
  const int b = tile >> 8;
  const int ty = (tile >> 3) & 31;
  const int tx = tile & 7;
  const int pg = threadIdx.x >> 2;        // 0..63
  const int sub = threadIdx.x & 3;
  const int yy = pg >> 4, xx = pg & 15;
  const int h = (ty << 2) | yy, w = (tx << 4) | xx;
  const int q = (b << 14) | (h << 7) | w;
  const ushort* wsq = ws16 + q;
  const ushort* xg = x16 + (((size_t)((g << 2) | b)) << 19) + (sub << 3);

  // softmax over the group's 9 logits (fp16 planes)
  float mk9[9];
  {
    float mx = -1e30f;
#pragma unroll
    for (int p = 0; p < 9; ++p) {
      mk9[p] = h2f(wsq[(size_t)(72 + g * 9 + p) * NPIX]);
      mx = fmaxf(mx, mk9[p]);
    }
    float s = 0.f;
#pragma unroll
    for (int p = 0; p < 9; ++p) {
      mk9[p] = __expf(mk9[p] - mx);
      s += mk9[p];
    }
    const float sinv = 1.0f / s;
#pragma unroll
    for (int p = 0; p < 9; ++p) mk9[p] *= sinv;
  }

  float a0 = 0.f, a1 = 0.f, a2 = 0.f, a3 = 0.f;
  float a4 = 0.f, a5 = 0.f, a6 = 0.f, a7 = 0.f;

#pragma unroll
  for (int bt = 0; bt < 3; ++bt) {
    float w00[3], w10[3], w01[3], w11[3];
    int o00[3], o10[3], o01[3], o11[3];
#pragma unroll
    for (int i = 0; i < 3; ++i) {
      const int p = bt * 3 + i;
      const float offx = h2f(wsq[(size_t)(g * 18 + 2 * p) * NPIX]);
      const float offy = h2f(wsq[(size_t)(g * 18 + 2 * p + 1) * NPIX]);
      const float px = (float)(w + p / 3) + offx;
      const float py = (float)(h + p % 3) + offy;
      const float fx = floorf(px), fy = floorf(py);
      const float txf = px - fx, tyf = py - fy;
      const int x0 = (int)fx - 1, y0 = (int)fy - 1;
      const int x1 = x0 + 1, y1 = y0 + 1;
      const float ax0 = ((unsigned)x0 < 128u) ? (1.f - txf) : 0.f;
      const float ax1 = ((unsigned)x1 < 128u) ? txf : 0.f;
      const float ay0 = ((unsigned)y0 < 128u) ? (mk9[p] * (1.f - tyf)) : 0.f;
      const float ay1 = ((unsigned)y1 < 128u) ? (mk9[p] * tyf) : 0.f;
      w00[i] = ax0 * ay0; w10[i] = ax1 * ay0;
      w01[i] = ax0 * ay1; w11[i] = ax1 * ay1;
      const int cx0 = min(max(x0, 0), 127), cy0 = min(max(y0, 0), 127);
      const int cx1 = min(max(x1, 0), 127), cy1 = min(max(y1, 0), 127);
      o00[i] = ((cy0 << 7) | cx0) << 5;
      o10[i] = ((cy0 << 7) | cx1) << 5;
      o01[i] = ((cy1 << 7) | cx0) << 5;
      o11[i] = ((cy1 << 7) | cx1) << 5;
    }
    uint4 d00[3], d10[3], d01[3], d11[3];
#pragma unroll
    for (int i = 0; i < 3; ++i) {
      d00[i] = *(const uint4*)(xg + o00[i]);
      d10[i] = *(const uint4*)(xg + o10[i]);
      d01[i] = *(const uint4*)(xg + o01[i]);
      d11[i] = *(const uint4*)(xg + o11[i]);
    }
#pragma unroll
    for (int i = 0; i < 3; ++i) {
      a0 = fmaf(w00[i], bflo(d00[i].x), fmaf(w10[i], bflo(d10[i].x),
           fmaf(w01[i], bflo(d01[i].x), fmaf(w11[i], bflo(d11[i].x), a0))));
      a1 = fmaf(w00[i], bfhi(d00[i].x), fmaf(w10[i], bfhi(d10[i].x),
           fmaf(w01[i], bfhi(d01[i].x), fmaf(w11[i], bfhi(d11[i].x), a1))));
      a2 = fmaf(w00[i], bflo(d00[i].y), fmaf(w10[i], bflo(d10[i].y),
           fmaf(w01[i], bflo(d01[i].y), fmaf(w11[i], bflo(d11[i].y), a2))));
      a3 = fmaf(w00[i], bfhi(d00[i].y), fmaf(w10[i], bfhi(d10[i].y),
           fmaf(w01[i], bfhi(d01[i].y), fmaf(w11[i], bfhi(d11[i].y), a3))));
      a4 = fmaf(w00[i], bflo(d00[i].z), fmaf(w10[i], bflo(d10[i].z),
           fmaf(w01[i], bflo(d01[i].z), fmaf(w11[i], bflo(d11[i].z), a4))));
      a5 = fmaf(w00[i], bfhi(d00[i].z), fmaf(w10[i], bfhi(d10[i].z),
           fmaf(w01[i], bfhi(d01[i].z), fmaf(w11[i], bfhi(d11[i].z), a5))));
      a6 = fmaf(w00[i], bflo(d00[i].w), fmaf(w10[i], bflo(d10[i].w),
           fmaf(w01[i], bflo(d01[i].w), fmaf(w11[i], bflo(d11[i].w), a6))));
      a7 = fmaf(w00[i], bfhi(d00[i].w), fmaf(w10[i], bfhi(d10[i].w),
           fmaf(w01[i], bfhi(d01[i].w), fmaf(w11[i], bfhi(d11[i].w), a7))));
    }
  }

  float* op = out + (size_t)q * 128 + (g << 5) + (sub << 3);
  float4 oa, ob;
  oa.x = a0; oa.y = a1; oa.z = a2; oa.w = a3;
  ob.x = a4; ob.y = a5; ob.z = a6; ob.w = a7;
  *(float4*)op = oa;
  *(float4*)(op + 4) = ob;
}

// ---------------- Tier-2 fallback: legacy VALU lin (with softmax) ----------
__global__ __launch_bounds__(256) void dcn_lin(
    const float* __restrict__ x, const float* __restrict__ Woff,
    const float* __restrict__ boff, const float* __restrict__ Wmask,
    const float* __restrict__ bmask, float* __restrict__ ws) {
  const int jg = blockIdx.x >> 8;
  const int pix = ((blockIdx.x & 255) << 8) | threadIdx.x;
  const float* W;
  const float* bias;
  int ldw, obase;
  if (jg == 0) {
    W = Woff; bias = boff; ldw = 72; obase = 0;
  } else if (jg == 1) {
    W = Woff + 36; bias = boff + 36; ldw = 72; obase = 36;
  } else {
    W = Wmask; bias = bmask; ldw = 36; obase = 72;
  }
  float acc[36];
#pragma unroll
  for (int j = 0; j < 36; ++j) acc[j] = bias[j];
  const float* xp = x + (size_t)pix * 128;
  for (int c0 = 0; c0 < 128; c0 += 8) {
    float xr[8];
    *(float4*)(xr) = *(const float4*)(xp + c0);
    *(float4*)(xr + 4) = *(const float4*)(xp + c0 + 4);
#pragma unroll
    for (int cc = 0; cc < 8; ++cc) {
      const float xc = xr[cc];
      const float* wr = W + (size_t)(c0 + cc) * ldw;
#pragma unroll
      for (int j = 0; j < 36; ++j) acc[j] = fmaf(xc, wr[j], acc[j]);
    }
  }
  if (jg == 2) {
#pragma unroll
    for (int g = 0; g < 4; ++g) {
      float mx = acc[g * 9];
#pragma unroll
      for (int p = 1; p < 9; ++p) mx = fmaxf(mx, acc[g * 9 + p]);
      float s = 0.f;
#pragma unroll
      for (int p = 0; p < 9; ++p) {
        acc[g * 9 + p] = __expf(acc[g * 9 + p] - mx);
        s += acc[g * 9 + p];
      }
      const float sinv = 1.0f / s;
#pragma unroll
      for (int p = 0; p < 9; ++p) acc[g * 9 + p] *= sinv;
    }
  }
#pragma unroll
  for (int j = 0; j < 36; ++j) ws[(size_t)(obase + j) * NPIX + pix] = acc[j];
}

// ---------------- Tier-2 fallback: fp32 gather (R2-proven) ----------------
__global__ __launch_bounds__(256) void dcn_samp_f32(
    const float* __restrict__ x, const float* __restrict__ ws,
    float* __restrict__ out) {
  const int q = (blockIdx.x << 4) | (threadIdx.x >> 4);
  const int sub = threadIdx.x & 15;
  const int c = sub << 3;
  const int g = sub >> 2;
  const int b = q >> 14;
  const int h = (q >> 7) & 127;
  const int w = q & 127;
  const float* xb = x + ((size_t)b << 21) + c;
  const float* wsq = ws + q;
  float a0 = 0.f, a1 = 0.f, a2 = 0.f, a3 = 0.f;
  float a4 = 0.f, a5 = 0.f, a6 = 0.f, a7 = 0.f;
#pragma unroll
  for (int p = 0; p < 9; ++p) {
    const float offx = wsq[(size_t)(g * 18 + p * 2) * NPIX];
    const float offy = wsq[(size_t)(g * 18 + p * 2 + 1) * NPIX];
    const float mk = wsq[(size_t)(72 + g * 9 + p) * NPIX];
    const float px = (float)(w + p / 3) + offx;
    const float py = (float)(h + p % 3) + offy;
    const float fx = floorf(px), fy = floorf(py);
    const float tx = px - fx, ty = py - fy;
    const int x0 = (int)fx - 1, y0 = (int)fy - 1;
    const int x1 = x0 + 1, y1 = y0 + 1;
    const float ax0 = ((unsigned)x0 < 128u) ? (1.f - tx) : 0.f;
    const float ax1 = ((unsigned)x1 < 128u) ? tx : 0.f;
    const float ay0 = ((unsigned)y0 < 128u) ? (mk * (1.f - ty)) : 0.f;
    const float ay1 = ((unsigned)y1 < 128u) ? (mk * ty) : 0.f;
    const float w00 = ax0 * ay0, w10 = ax1 * ay0;
    const float w01 = ax0 * ay1, w11 = ax1 * ay1;
    const int cx0 = min(max(x0, 0), 127), cy0 = min(max(y0, 0), 127);
    const int cx1 = min(max(x1, 0), 127), cy1 = min(max(y1, 0), 127);
    const int o00 = (cy0 << 14) | (cx0 << 7), o10 = (cy0 << 14) | (cx1 << 7);
    const int o01 = (cy1 << 14) | (cx0 << 7), o11 = (cy1 << 14) | (cx1 << 7);
    const float4 v00a = *(const float4*)(xb + o00);
    const float4 v00b = *(const float4*)(xb + o00 + 4);
    const float4 v10a = *(const float4*)(xb + o10);
    const float4 v10b = *(const float4*)(xb + o10 + 4);
    const float4 v01a = *(const float4*)(xb + o01);
    const float4 v01b = *(const float4*)(xb + o01 + 4);
    const float4 v11a = *(const float4*)(xb + o11);
    const float4 v11b = *(const float4*)(xb + o11 + 4);
    a0 = fmaf(w00, v00a.x, fmaf(w10, v10a.x, fmaf(w01, v01a.x, fmaf(w11, v11a.x, a0))));
    a1 = fmaf(w00, v00a.y, fmaf(w10, v10a.y, fmaf(w01, v01a.y, fmaf(w11, v11a.y, a1))));
    a2 = fmaf(w00, v00a.z, fmaf(w10, v10a.z, fmaf(w01, v01a.z, fmaf(w11, v11a.z, a2))));
    a3 = fmaf(w00, v00a.w, fmaf(w10, v10a.w, fmaf(w01, v01a.w, fmaf(w11, v11a.w, a3))));
    a4 = fmaf(w00, v00b.x, fmaf(w10, v10b.x, fmaf(w01, v01b.x, fmaf(w11, v11b.x, a4))));
    a5 = fmaf(w00, v00b.y, fmaf(w10, v10b.y, fmaf(w01, v01b.y, fmaf(w11, v11b.y, a5))));
    a6 = fmaf(w00, v00b.z, fmaf(w10, v10b.z, fmaf(w01, v01b.z, fmaf(w11, v11b.z, a6))));
    a7 = fmaf(w00, v00b.w, fmaf(w10, v10b.w, fmaf(w01, v01b.w, fmaf(w11, v11b.w, a7))));
  }
  float4 oa, ob;
  oa.x = a0; oa.y = a1; oa.z = a2; oa.w = a3;
  ob.x = a4; ob.y = a5; ob.z = a6; ob.w = a7;
  float* op = out + (size_t)q * 128 + c;
  *(float4*)op = oa;
  *(float4*)(op + 4) = ob;
}

// ---------------- Tier-3 fallback: fully fused ----------------
__global__ __launch_bounds__(128) void dcn_fused(
    const float* __restrict__ x, const float* __restrict__ Woff,
    const float* __restrict__ boff, const float* __restrict__ Wmask,
    const float* __restrict__ bmask, float* __restrict__ out) {
  __shared__ float xs[128];
  __shared__ float res[108];
  __shared__ float msk[36];
  const int q = blockIdx.x;
  const int t = threadIdx.x;
  const int b = q >> 14, h = (q >> 7) & 127, w = q & 127;
  xs[t] = x[(size_t)q * 128 + t];
  __syncthreads();
  if (t < 108) {
    float a;
    const float* W;
    int ld;
    if (t < 72) {
      a = boff[t]; W = Woff + t; ld = 72;
    } else {
      a = bmask[t - 72]; W = Wmask + (t - 72); ld = 36;
    }
    for (int cc = 0; cc < 128; ++cc) a = fmaf(xs[cc], W[(size_t)cc * ld], a);
    res[t] = a;
  }
  __syncthreads();
  if (t < 4) {
    float mx = -1e30f;
    for (int p = 0; p < 9; ++p) mx = fmaxf(mx, res[72 + t * 9 + p]);
    float s = 0.f;
    float e[9];
    for (int p = 0; p < 9; ++p) {
      e[p] = __expf(res[72 + t * 9 + p] - mx);
      s += e[p];
    }
    for (int p = 0; p < 9; ++p) msk[t * 9 + p] = e[p] / s;
  }
  __syncthreads();
  const int g = t >> 5;
  const float* xb = x + ((size_t)b << 21) + t;
  float acc = 0.f;
#pragma unroll
  for (int p = 0; p < 9; ++p) {
    const float offx = res[g * 18 + p * 2];
    const float offy = res[g * 18 + p * 2 + 1];
    const float px = (float)(w + p / 3) + offx;
    const float py = (float)(h + p % 3) + offy;
    const float fx = floorf(px), fy = floorf(py);
    const float tx = px - fx, ty = py - fy;
    const int x0 = (int)fx - 1, y0 = (int)fy - 1;
    float sv = 0.f;
#define CORNER1(XI, YI, WT)                                       \
  if ((unsigned)(XI) < 128u && (unsigned)(YI) < 128u)             \
    sv = fmaf((WT), xb[((size_t)(YI) << 14) + ((size_t)(XI) << 7)], sv);
    CORNER1(x0, y0, (1.f - tx) * (1.f - ty))
    CORNER1(x0 + 1, y0, tx * (1.f - ty))
    CORNER1(x0, y0 + 1, (1.f - tx) * ty)
    CORNER1(x0 + 1, y0 + 1, tx * ty)
#undef CORNER1
    acc = fmaf(msk[g * 9 + p], sv, acc);
  }
  out[(size_t)q * 128 + t] = acc;
}

extern "C" void kernel_launch(void* const* d_in, const int* in_sizes, int n_in,
                              void* d_out, int out_size, void* d_ws,
                              size_t ws_size, hipStream_t stream) {
  const float* x = (const float*)d_in[0];
  const float* Woff = (const float*)d_in[1];
  const float* boff = (const float*)d_in[2];
  const float* Wmask = (const float*)d_in[3];
  const float* bmask = (const float*)d_in[4];
  float* out = (float*)d_out;
  const size_t need_ws = (size_t)NPIX * 108 * sizeof(float);
  const size_t need_full = (size_t)NPIX * (128 + 108) * sizeof(ushort);
  if (ws_size >= need_full) {
    ushort* x16 = (ushort*)d_ws;                      // 16 MB
    ushort* ws16 = (ushort*)d_ws + (size_t)NPIX * 128;  // 14.2 MB
    dcn_lin_mfma<<<1024, 256, 0, stream>>>(x, Woff, boff, Wmask, bmask, ws16,
                                           x16);
    dcn_samp<<<4096, 256, 0, stream>>>(x16, ws16, out);
  } else if (ws_size >= need_ws) {
    float* ws = (float*)d_ws;
    dcn_lin<<<768, 256, 0, stream>>>(x, Woff, boff, Wmask, bmask, ws);
    dcn_samp_f32<<<4096, 256, 0, stream>>>(x, ws, out);
  } else {
    dcn_fused<<<NPIX, 128, 0, stream>>>(x, Woff, boff, Wmask, bmask, out);
  }
}

// Round 8
// 62.049 us; speedup vs baseline: 2.0141x; 2.0141x over previous
//
#include <hip/hip_runtime.h>

// DCNv3 forward, fp32 in/out. Layouts (from the reference's view-reshapes):
//   x   : (B=4, H=128, W=128, C=128) flat — idx = ((b*128+h)*128+w)*128+c
//   out : same
//   W_off (128,72), b_off(72), W_mask(128,36), b_mask(36)
// Tier-1 ws layout:
//   [0)            x16 : bf16 copy of x, GROUP-PLANAR (16 MB):
//                  x16[((g*4+b)*16384 + y*128 + x)*32 + ch], ch in [0,32)
//   [NPIX*128*2)   ws16: fp16 SoA planes (14.2 MB): ws16[j*NPIX + pix]
//                  j<72 = offsets (g,p,2); j in [72,108) = mask LOGITS
//                  (softmax done in samp).
// R7 lesson: no register-array load batching — 12 uint4 in flight spilled to
// scratch (466 MB HBM traffic). Keep the 1-point loop, named scalars only.

#define NPIX 65536  // B*H*W

typedef unsigned int uint;
typedef unsigned short ushort;
typedef __attribute__((ext_vector_type(8))) short short8v;   // 8 bf16
typedef __attribute__((ext_vector_type(4))) float f32x4;

__device__ __forceinline__ ushort f2bf(float f) {
  uint u = __float_as_uint(f);
  u += 0x7FFFu + ((u >> 16) & 1u);  // RNE
  return (ushort)(u >> 16);
}
__device__ __forceinline__ uint pkbf(float lo, float hi) {
  return (uint)f2bf(lo) | ((uint)f2bf(hi) << 16);
}
__device__ __forceinline__ float bflo(uint d) { return __uint_as_float(d << 16); }
__device__ __forceinline__ float bfhi(uint d) { return __uint_as_float(d & 0xFFFF0000u); }
__device__ __forceinline__ ushort f2h(float f) {
  union { _Float16 h; ushort u; } cv;
  cv.h = (_Float16)f;
  return cv.u;
}
__device__ __forceinline__ float h2f(ushort u) {
  union { ushort u; _Float16 h; } cv;
  cv.u = u;
  return (float)cv.h;
}

union U8 { uint u[4]; short8v v; };

// ---------------- Kernel A: MFMA linear layers + fused bf16 pack -----------
// grid 1024, block 256 (4 waves). Wave = 16 pixels x 112 cols (7 N-tiles),
// K=128 (4 k-tiles of 32). W^T staged in LDS as bf16 pairs, stride 68 u32.
// C/D layout (m89-verified): col=lane&15 (output col n), row=(lane>>4)*4+reg
// (pixel) -> acc[nt] is 4 consecutive pixels of one ws plane -> ushort4 store.
__global__ __launch_bounds__(256) void dcn_lin_mfma(
    const float* __restrict__ x, const float* __restrict__ Woff,
    const float* __restrict__ boff, const float* __restrict__ Wmask,
    const float* __restrict__ bmask, ushort* __restrict__ ws16,
    ushort* __restrict__ x16) {
  __shared__ uint wt[112 * 68];
  __shared__ float bias_lds[112];
  const int pbase = blockIdx.x << 6;  // 64 pixels per block
  const int t = threadIdx.x;

  // ---- stage W^T (bf16 k-pairs) into LDS: wt[n*68 + k/2] ----
  {
    int n = t, row = 0;
    bool act = true;
    if (t >= 224) act = false;
    else if (t >= 112) { n = t - 112; row = 1; }
    if (act) {
      for (int kp = row; kp < 64; kp += 2) {
        const int k = kp << 1;
        float w0, w1;
        if (n < 72) {
          w0 = Woff[k * 72 + n];        w1 = Woff[k * 72 + 72 + n];
        } else if (n < 108) {
          w0 = Wmask[k * 36 + n - 72];  w1 = Wmask[k * 36 + 36 + n - 72];
        } else {
          w0 = 0.f; w1 = 0.f;
        }
        wt[n * 68 + kp] = pkbf(w0, w1);
      }
    }
    if (t < 112)
      bias_lds[t] = (t < 72) ? boff[t] : (t < 108 ? bmask[t - 72] : 0.f);
  }

  // ---- fused bf16 group-planar pack (no LDS dependency) ----
  if (x16) {
    const int pix2 = pbase + (t >> 2);
    const int quad = t & 3;  // = group
    const float* xp = x + (size_t)pix2 * 128 + (quad << 5);
    const int bb = pix2 >> 14, yx = pix2 & 16383;
    ushort* dst = x16 + ((((size_t)((quad << 2) | bb) << 14) | yx) << 5);
#pragma unroll
    for (int ck = 0; ck < 2; ++ck) {
      const float4 a = *(const float4*)(xp + ck * 16);
      const float4 b4 = *(const float4*)(xp + ck * 16 + 4);
      const float4 c4 = *(const float4*)(xp + ck * 16 + 8);
      const float4 d4 = *(const float4*)(xp + ck * 16 + 12);
      uint4 s0, s1;
      s0.x = pkbf(a.x, a.y);   s0.y = pkbf(a.z, a.w);
      s0.z = pkbf(b4.x, b4.y); s0.w = pkbf(b4.z, b4.w);
      s1.x = pkbf(c4.x, c4.y); s1.y = pkbf(c4.z, c4.w);
      s1.z = pkbf(d4.x, d4.y); s1.w = pkbf(d4.z, d4.w);
      *(uint4*)(dst + ck * 16) = s0;
      *(uint4*)(dst + ck * 16 + 8) = s1;
    }
  }
  __syncthreads();

  // ---- MFMA ----
  const int wv = t >> 6;
  const int lane = t & 63;
  const int lrow = lane & 15;  // A-row (pixel) / B-col (n)
  const int lhi = lane >> 4;   // k sub-block
  const int pixrow = pbase + (wv << 4) + lrow;

  U8 afr[4];
#pragma unroll
  for (int kt = 0; kt < 4; ++kt) {
    const float* ax = x + (size_t)pixrow * 128 + (kt << 5) + (lhi << 3);
    const float4 xa = *(const float4*)ax;
    const float4 xb4 = *(const float4*)(ax + 4);
    afr[kt].u[0] = pkbf(xa.x, xa.y);   afr[kt].u[1] = pkbf(xa.z, xa.w);
    afr[kt].u[2] = pkbf(xb4.x, xb4.y); afr[kt].u[3] = pkbf(xb4.z, xb4.w);
  }

  f32x4 acc[7];
#pragma unroll
  for (int nt = 0; nt < 7; ++nt) {
    const float bv = bias_lds[(nt << 4) + lrow];
    f32x4 a4 = {bv, bv, bv, bv};
#pragma unroll
    for (int kt = 0; kt < 4; ++kt) {
      U8 bfr;
      const uint4 bw =
          *(const uint4*)(wt + ((nt << 4) + lrow) * 68 + (kt << 4) + (lhi << 2));
      bfr.u[0] = bw.x; bfr.u[1] = bw.y; bfr.u[2] = bw.z; bfr.u[3] = bw.w;
      a4 = __builtin_amdgcn_mfma_f32_16x16x32_bf16(afr[kt].v, bfr.v, a4, 0, 0, 0);
    }
    acc[nt] = a4;
  }

  // ---- epilogue: fp16 ushort4 stores into SoA ws16 ----
  const int rowb = pbase + (wv << 4) + (lhi << 2);
#pragma unroll
  for (int nt = 0; nt < 7; ++nt) {
    const int n = (nt << 4) + lrow;
    if (n < 108) {
      ushort4 hv;
      hv.x = f2h(acc[nt].x);
      hv.y = f2h(acc[nt].y);
      hv.z = f2h(acc[nt].z);
      hv.w = f2h(acc[nt].w);
      *(ushort4*)(ws16 + (size_t)n * NPIX + rowb) = hv;
    }
  }
}

// ---------------- Kernel B: bilinear gather from bf16 planar ---------------
// R6-proven structure: block 256 = 64 consecutive (pixel,group) pairs x 4
// chunk-lanes; g = blockIdx&3. 1-point loop, loads consumed immediately
// (no register arrays -> no scratch). ws reads are fp16 planes.
__global__ __launch_bounds__(256) void dcn_samp(
    const ushort* __restrict__ x16, const ushort* __restrict__ ws16,
    float* __restrict__ out) {
  const int g = blockIdx.x & 3;
  const int pg = threadIdx.x >> 2;   // 0..63: pixel within block
  const int sub = threadIdx.x & 3;   // 16B chunk within the group slice
  const int q = ((blockIdx.x >> 2) << 6) | pg;
  const int b = q >> 14;
  const int h = (q >> 7) & 127;
  const int w = q & 127;
  const ushort* wsq = ws16 + q;
  const ushort* xg = x16 + (((size_t)((g << 2) | b)) << 19) + (sub << 3);

  // softmax over the group's 9 logits (fp16 planes)
  float mk9[9];
  {
    float mx = -1e30f;
#pragma unroll
    for (int p = 0; p < 9; ++p) {
      mk9[p] = h2f(wsq[(size_t)(72 + g * 9 + p) * NPIX]);
      mx = fmaxf(mx, mk9[p]);
    }
    float s = 0.f;
#pragma unroll
    for (int p = 0; p < 9; ++p) {
      mk9[p] = __expf(mk9[p] - mx);
      s += mk9[p];
    }
    const float sinv = 1.0f / s;
#pragma unroll
    for (int p = 0; p < 9; ++p) mk9[p] *= sinv;
  }

  float a0 = 0.f, a1 = 0.f, a2 = 0.f, a3 = 0.f;
  float a4 = 0.f, a5 = 0.f, a6 = 0.f, a7 = 0.f;

#pragma unroll
  for (int p = 0; p < 9; ++p) {
    const float offx = h2f(wsq[(size_t)(g * 18 + 2 * p) * NPIX]);
    const float offy = h2f(wsq[(size_t)(g * 18 + 2 * p + 1) * NPIX]);
    const float mk = mk9[p];
    const float px = (float)(w + p / 3) + offx;
    const float py = (float)(h + p % 3) + offy;
    const float fx = floorf(px), fy = floorf(py);
    const float tx = px - fx, ty = py - fy;
    const int x0 = (int)fx - 1, y0 = (int)fy - 1;
    const int x1 = x0 + 1, y1 = y0 + 1;
    const float ax0 = ((unsigned)x0 < 128u) ? (1.f - tx) : 0.f;
    const float ax1 = ((unsigned)x1 < 128u) ? tx : 0.f;
    const float ay0 = ((unsigned)y0 < 128u) ? (mk * (1.f - ty)) : 0.f;
    const float ay1 = ((unsigned)y1 < 128u) ? (mk * ty) : 0.f;
    const float w00 = ax0 * ay0, w10 = ax1 * ay0;
    const float w01 = ax0 * ay1, w11 = ax1 * ay1;
    const int cx0 = min(max(x0, 0), 127), cy0 = min(max(y0, 0), 127);
    const int cx1 = min(max(x1, 0), 127), cy1 = min(max(y1, 0), 127);
    const int o00 = ((cy0 << 7) | cx0) << 5;
    const int o10 = ((cy0 << 7) | cx1) << 5;
    const int o01 = ((cy1 << 7) | cx0) << 5;
    const int o11 = ((cy1 << 7) | cx1) << 5;
    const uint4 d00 = *(const uint4*)(xg + o00);
    const uint4 d10 = *(const uint4*)(xg + o10);
    const uint4 d01 = *(const uint4*)(xg + o01);
    const uint4 d11 = *(const uint4*)(xg + o11);
    a0 = fmaf(w00, bflo(d00.x), fmaf(w10, bflo(d10.x),
         fmaf(w01, bflo(d01.x), fmaf(w11, bflo(d11.x), a0))));
    a1 = fmaf(w00, bfhi(d00.x), fmaf(w10, bfhi(d10.x),
         fmaf(w01, bfhi(d01.x), fmaf(w11, bfhi(d11.x), a1))));
    a2 = fmaf(w00, bflo(d00.y), fmaf(w10, bflo(d10.y),
         fmaf(w01, bflo(d01.y), fmaf(w11, bflo(d11.y), a2))));
    a3 = fmaf(w00, bfhi(d00.y), fmaf(w10, bfhi(d10.y),
         fmaf(w01, bfhi(d01.y), fmaf(w11, bfhi(d11.y), a3))));
    a4 = fmaf(w00, bflo(d00.z), fmaf(w10, bflo(d10.z),
         fmaf(w01, bflo(d01.z), fmaf(w11, bflo(d11.z), a4))));
    a5 = fmaf(w00, bfhi(d00.z), fmaf(w10, bfhi(d10.z),
         fmaf(w01, bfhi(d01.z), fmaf(w11, bfhi(d11.z), a5))));
    a6 = fmaf(w00, bflo(d00.w), fmaf(w10, bflo(d10.w),
         fmaf(w01, bflo(d01.w), fmaf(w11, bflo(d11.w), a6))));
    a7 = fmaf(w00, bfhi(d00.w), fmaf(w10, bfhi(d10.w),
         fmaf(w01, bfhi(d01.w), fmaf(w11, bfhi(d11.w), a7))));
  }

  float* op = out + (size_t)q * 128 + (g << 5) + (sub << 3);
  float4 oa, ob;
  oa.x = a0; oa.y = a1; oa.z = a2; oa.w = a3;
  ob.x = a4; ob.y = a5; ob.z = a6; ob.w = a7;
  *(float4*)op = oa;
  *(float4*)(op + 4) = ob;
}

// ---------------- Tier-2 fallback: legacy VALU lin (with softmax) ----------
__global__ __launch_bounds__(256) void dcn_lin(
    const float* __restrict__ x, const float* __restrict__ Woff,
    const float* __restrict__ boff, const float* __restrict__ Wmask,
    const float* __restrict__ bmask, float* __restrict__ ws) {
  const int jg = blockIdx.x >> 8;
  const int pix = ((blockIdx.x & 255) << 8) | threadIdx.x;
  const float* W;
  const float* bias;
  int ldw, obase;
  if (jg == 0) {
    W = Woff; bias = boff; ldw = 72; obase = 0;
  } else if (jg == 1) {
    W = Woff + 36; bias = boff + 36; ldw = 72; obase = 36;
  } else {
    W = Wmask; bias = bmask; ldw = 36; obase = 72;
  }
  float acc[36];
#pragma unroll
  for (int j = 0; j < 36; ++j) acc[j] = bias[j];
  const float* xp = x + (size_t)pix * 128;
  for (int c0 = 0; c0 < 128; c0 += 8) {
    float xr[8];
    *(float4*)(xr) = *(const float4*)(xp + c0);
    *(float4*)(xr + 4) = *(const float4*)(xp + c0 + 4);
#pragma unroll
    for (int cc = 0; cc < 8; ++cc) {
      const float xc = xr[cc];
      const float* wr = W + (size_t)(c0 + cc) * ldw;
#pragma unroll
      for (int j = 0; j < 36; ++j) acc[j] = fmaf(xc, wr[j], acc[j]);
    }
  }
  if (jg == 2) {
#pragma unroll
    for (int g = 0; g < 4; ++g) {
      float mx = acc[g * 9];
#pragma unroll
      for (int p = 1; p < 9; ++p) mx = fmaxf(mx, acc[g * 9 + p]);
      float s = 0.f;
#pragma unroll
      for (int p = 0; p < 9; ++p) {
        acc[g * 9 + p] = __expf(acc[g * 9 + p] - mx);
        s += acc[g * 9 + p];
      }
      const float sinv = 1.0f / s;
#pragma unroll
      for (int p = 0; p < 9; ++p) acc[g * 9 + p] *= sinv;
    }
  }
#pragma unroll
  for (int j = 0; j < 36; ++j) ws[(size_t)(obase + j) * NPIX + pix] = acc[j];
}

// ---------------- Tier-2 fallback: fp32 gather (R2-proven) ----------------
__global__ __launch_bounds__(256) void dcn_samp_f32(
    const float* __restrict__ x, const float* __restrict__ ws,
    float* __restrict__ out) {
  const int q = (blockIdx.x << 4) | (threadIdx.x >> 4);
  const int sub = threadIdx.x & 15;
  const int c = sub << 3;
  const int g = sub >> 2;
  const int b = q >> 14;
  const int h = (q >> 7) & 127;
  const int w = q & 127;
  const float* xb = x + ((size_t)b << 21) + c;
  const float* wsq = ws + q;
  float a0 = 0.f, a1 = 0.f, a2 = 0.f, a3 = 0.f;
  float a4 = 0.f, a5 = 0.f, a6 = 0.f, a7 = 0.f;
#pragma unroll
  for (int p = 0; p < 9; ++p) {
    const float offx = wsq[(size_t)(g * 18 + p * 2) * NPIX];
    const float offy = wsq[(size_t)(g * 18 + p * 2 + 1) * NPIX];
    const float mk = wsq[(size_t)(72 + g * 9 + p) * NPIX];
    const float px = (float)(w + p / 3) + offx;
    const float py = (float)(h + p % 3) + offy;
    const float fx = floorf(px), fy = floorf(py);
    const float tx = px - fx, ty = py - fy;
    const int x0 = (int)fx - 1, y0 = (int)fy - 1;
    const int x1 = x0 + 1, y1 = y0 + 1;
    const float ax0 = ((unsigned)x0 < 128u) ? (1.f - tx) : 0.f;
    const float ax1 = ((unsigned)x1 < 128u) ? tx : 0.f;
    const float ay0 = ((unsigned)y0 < 128u) ? (mk * (1.f - ty)) : 0.f;
    const float ay1 = ((unsigned)y1 < 128u) ? (mk * ty) : 0.f;
    const float w00 = ax0 * ay0, w10 = ax1 * ay0;
    const float w01 = ax0 * ay1, w11 = ax1 * ay1;
    const int cx0 = min(max(x0, 0), 127), cy0 = min(max(y0, 0), 127);
    const int cx1 = min(max(x1, 0), 127), cy1 = min(max(y1, 0), 127);
    const int o00 = (cy0 << 14) | (cx0 << 7), o10 = (cy0 << 14) | (cx1 << 7);
    const int o01 = (cy1 << 14) | (cx0 << 7), o11 = (cy1 << 14) | (cx1 << 7);
    const float4 v00a = *(const float4*)(xb + o00);
    const float4 v00b = *(const float4*)(xb + o00 + 4);
    const float4 v10a = *(const float4*)(xb + o10);
    const float4 v10b = *(const float4*)(xb + o10 + 4);
    const float4 v01a = *(const float4*)(xb + o01);
    const float4 v01b = *(const float4*)(xb + o01 + 4);
    const float4 v11a = *(const float4*)(xb + o11);
    const float4 v11b = *(const float4*)(xb + o11 + 4);
    a0 = fmaf(w00, v00a.x, fmaf(w10, v10a.x, fmaf(w01, v01a.x, fmaf(w11, v11a.x, a0))));
    a1 = fmaf(w00, v00a.y, fmaf(w10, v10a.y, fmaf(w01, v01a.y, fmaf(w11, v11a.y, a1))));
    a2 = fmaf(w00, v00a.z, fmaf(w10, v10a.z, fmaf(w01, v01a.z, fmaf(w11, v11a.z, a2))));
    a3 = fmaf(w00, v00a.w, fmaf(w10, v10a.w, fmaf(w01, v01a.w, fmaf(w11, v11a.w, a3))));
    a4 = fmaf(w00, v00b.x, fmaf(w10, v10b.x, fmaf(w01, v01b.x, fmaf(w11, v11b.x, a4))));
    a5 = fmaf(w00, v00b.y, fmaf(w10, v10b.y, fmaf(w01, v01b.y, fmaf(w11, v11b.y, a5))));
    a6 = fmaf(w00, v00b.z, fmaf(w10, v10b.z, fmaf(w01, v01b.z, fmaf(w11, v11b.z, a6))));
    a7 = fmaf(w00, v00b.w, fmaf(w10, v10b.w, fmaf(w01, v01b.w, fmaf(w11, v11b.w, a7))));
  }
  float4 oa, ob;
  oa.x = a0; oa.y = a1; oa.z = a2; oa.w = a3;
  ob.x = a4; ob.y = a5; ob.z = a6; ob.w = a7;
  float* op = out + (size_t)q * 128 + c;
  *(float4*)op = oa;
  *(float4*)(op + 4) = ob;
}

// ---------------- Tier-3 fallback: fully fused ----------------
__global__ __launch_bounds__(128) void dcn_fused(
    const float* __restrict__ x, const float* __restrict__ Woff,
    const float* __restrict__ boff, const float* __restrict__ Wmask,
    const float* __restrict__ bmask, float* __restrict__ out) {
  __shared__ float xs[128];
  __shared__ float res[108];
  __shared__ float msk[36];
  const int q = blockIdx.x;
  const int t = threadIdx.x;
  const int b = q >> 14, h = (q >> 7) & 127, w = q & 127;
  xs[t] = x[(size_t)q * 128 + t];
  __syncthreads();
  if (t < 108) {
    float a;
    const float* W;
    int ld;
    if (t < 72) {
      a = boff[t]; W = Woff + t; ld = 72;
    } else {
      a = bmask[t - 72]; W = Wmask + (t - 72); ld = 36;
    }
    for (int cc = 0; cc < 128; ++cc) a = fmaf(xs[cc], W[(size_t)cc * ld], a);
    res[t] = a;
  }
  __syncthreads();
  if (t < 4) {
    float mx = -1e30f;
    for (int p = 0; p < 9; ++p) mx = fmaxf(mx, res[72 + t * 9 + p]);
    float s = 0.f;
    float e[9];
    for (int p = 0; p < 9; ++p) {
      e[p] = __expf(res[72 + t * 9 + p] - mx);
      s += e[p];
    }
    for (int p = 0; p < 9; ++p) msk[t * 9 + p] = e[p] / s;
  }
  __syncthreads();
  const int g = t >> 5;
  const float* xb = x + ((size_t)b << 21) + t;
  float acc = 0.f;
#pragma unroll
  for (int p = 0; p < 9; ++p) {
    const float offx = res[g * 18 + p * 2];
    const float offy = res[g * 18 + p * 2 + 1];
    const float px = (float)(w + p / 3) + offx;
    const float py = (float)(h + p % 3) + offy;
    const float fx = floorf(px), fy = floorf(py);
    const float tx = px - fx, ty = py - fy;
    const int x0 = (int)fx - 1, y0 = (int)fy - 1;
    float sv = 0.f;
#define CORNER1(XI, YI, WT)                                       \
  if ((unsigned)(XI) < 128u && (unsigned)(YI) < 128u)             \
    sv = fmaf((WT), xb[((size_t)(YI) << 14) + ((size_t)(XI) << 7)], sv);
    CORNER1(x0, y0, (1.f - tx) * (1.f - ty))
    CORNER1(x0 + 1, y0, tx * (1.f - ty))
    CORNER1(x0, y0 + 1, (1.f - tx) * ty)
    CORNER1(x0 + 1, y0 + 1, tx * ty)
#undef CORNER1
    acc = fmaf(msk[g * 9 + p], sv, acc);
  }
  out[(size_t)q * 128 + t] = acc;
}

extern "C" void kernel_launch(void* const* d_in, const int* in_sizes, int n_in,
                              void* d_out, int out_size, void* d_ws,
                              size_t ws_size, hipStream_t stream) {
  const float* x = (const float*)d_in[0];
  const float* Woff = (const float*)d_in[1];
  const float* boff = (const float*)d_in[2];
  const float* Wmask = (const float*)d_in[3];
  const float* bmask = (const float*)d_in[4];
  float* out = (float*)d_out;
  const size_t need_ws = (size_t)NPIX * 108 * sizeof(float);
  const size_t need_full = (size_t)NPIX * (128 + 108) * sizeof(ushort);
  if (ws_size >= need_full) {
    ushort* x16 = (ushort*)d_ws;                        // 16 MB
    ushort* ws16 = (ushort*)d_ws + (size_t)NPIX * 128;  // 14.2 MB
    dcn_lin_mfma<<<1024, 256, 0, stream>>>(x, Woff, boff, Wmask, bmask, ws16,
                                           x16);
    dcn_samp<<<4096, 256, 0, stream>>>(x16, ws16, out);
  } else if (ws_size >= need_ws) {
    float* ws = (float*)d_ws;
    dcn_lin<<<768, 256, 0, stream>>>(x, Woff, boff, Wmask, bmask, ws);
    dcn_samp_f32<<<4096, 256, 0, stream>>>(x, ws, out);
  } else {
    dcn_fused<<<NPIX, 128, 0, stream>>>(x, Woff, boff, Wmask, bmask, out);
  }
}

// Round 9
// 60.874 us; speedup vs baseline: 2.0530x; 1.0193x over previous
//
#include <hip/hip_runtime.h>

// DCNv3 forward, fp32 in/out. Layouts (from the reference's view-reshapes):
//   x   : (B=4, H=128, W=128, C=128) flat — idx = ((b*128+h)*128+w)*128+c
//   out : same
//   W_off (128,72), b_off(72), W_mask(128,36), b_mask(36)
// Tier-1 ws layout:
//   [0)            x16 : bf16 copy of x, GROUP-PLANAR (16 MB):
//                  x16[((g*4+b)*16384 + y*128 + x)*32 + ch], ch in [0,32)
//   [NPIX*128*2)   ws16: fp16 AoS records (16.8 MB):
//                  per (pixel,group) 64B record at ws16[pix*128 + g*32]
//                  (ushort units): [0..17]=offsets (x,y per point),
//                  [18..26]=mask logits, [27..31]=pad (never read).
// R7 lesson: no register-array load batching (scratch spill). The AoS record
// gives the same MLP effect via 4 vector loads + compile-time extraction.

#define NPIX 65536  // B*H*W

typedef unsigned int uint;
typedef unsigned short ushort;
typedef __attribute__((ext_vector_type(8))) short short8v;   // 8 bf16
typedef __attribute__((ext_vector_type(4))) float f32x4;

__device__ __forceinline__ ushort f2bf(float f) {
  uint u = __float_as_uint(f);
  u += 0x7FFFu + ((u >> 16) & 1u);  // RNE
  return (ushort)(u >> 16);
}
__device__ __forceinline__ uint pkbf(float lo, float hi) {
  return (uint)f2bf(lo) | ((uint)f2bf(hi) << 16);
}
__device__ __forceinline__ float bflo(uint d) { return __uint_as_float(d << 16); }
__device__ __forceinline__ float bfhi(uint d) { return __uint_as_float(d & 0xFFFF0000u); }
__device__ __forceinline__ ushort f2h(float f) {
  union { _Float16 h; ushort u; } cv;
  cv.h = (_Float16)f;
  return cv.u;
}
__device__ __forceinline__ float h2f_lo(uint u) {
  union { ushort s; _Float16 h; } cv;
  cv.s = (ushort)(u & 0xFFFFu);
  return (float)cv.h;
}
__device__ __forceinline__ float h2f_hi(uint u) {
  union { ushort s; _Float16 h; } cv;
  cv.s = (ushort)(u >> 16);
  return (float)cv.h;
}

union U8 { uint u[4]; short8v v; };

// ---------------- Kernel A: MFMA linear layers + fused bf16 pack -----------
// grid 1024, block 256 (4 waves). Wave = 16 pixels x 112 cols (7 N-tiles),
// K=128 (4 k-tiles of 32). W^T staged in LDS as bf16 pairs, stride 68 u32.
// C/D layout (m89-verified): col=lane&15 (output col n), row=(lane>>4)*4+reg
// (pixel). Epilogue: fp16 transpose through LDS (reusing wt) -> AoS records,
// then a fully-coalesced 16KB block copy to ws16.
__global__ __launch_bounds__(256) void dcn_lin_mfma(
    const float* __restrict__ x, const float* __restrict__ Woff,
    const float* __restrict__ boff, const float* __restrict__ Wmask,
    const float* __restrict__ bmask, ushort* __restrict__ ws16,
    ushort* __restrict__ x16) {
  __shared__ uint wt[112 * 68];  // 30.4 KB; reused as 16KB fp16 scratch later
  __shared__ float bias_lds[112];
  const int pbase = blockIdx.x << 6;  // 64 pixels per block
  const int t = threadIdx.x;

  // ---- stage W^T (bf16 k-pairs) into LDS: wt[n*68 + k/2] ----
  {
    int n = t, row = 0;
    bool act = true;
    if (t >= 224) act = false;
    else if (t >= 112) { n = t - 112; row = 1; }
    if (act) {
      for (int kp = row; kp < 64; kp += 2) {
        const int k = kp << 1;
        float w0, w1;
        if (n < 72) {
          w0 = Woff[k * 72 + n];        w1 = Woff[k * 72 + 72 + n];
        } else if (n < 108) {
          w0 = Wmask[k * 36 + n - 72];  w1 = Wmask[k * 36 + 36 + n - 72];
        } else {
          w0 = 0.f; w1 = 0.f;
        }
        wt[n * 68 + kp] = pkbf(w0, w1);
      }
    }
    if (t < 112)
      bias_lds[t] = (t < 72) ? boff[t] : (t < 108 ? bmask[t - 72] : 0.f);
  }

  // ---- fused bf16 group-planar pack (no LDS dependency) ----
  if (x16) {
    const int pix2 = pbase + (t >> 2);
    const int quad = t & 3;  // = group
    const float* xp = x + (size_t)pix2 * 128 + (quad << 5);
    const int bb = pix2 >> 14, yx = pix2 & 16383;
    ushort* dst = x16 + ((((size_t)((quad << 2) | bb) << 14) | yx) << 5);
#pragma unroll
    for (int ck = 0; ck < 2; ++ck) {
      const float4 a = *(const float4*)(xp + ck * 16);
      const float4 b4 = *(const float4*)(xp + ck * 16 + 4);
      const float4 c4 = *(const float4*)(xp + ck * 16 + 8);
      const float4 d4 = *(const float4*)(xp + ck * 16 + 12);
      uint4 s0, s1;
      s0.x = pkbf(a.x, a.y);   s0.y = pkbf(a.z, a.w);
      s0.z = pkbf(b4.x, b4.y); s0.w = pkbf(b4.z, b4.w);
      s1.x = pkbf(c4.x, c4.y); s1.y = pkbf(c4.z, c4.w);
      s1.z = pkbf(d4.x, d4.y); s1.w = pkbf(d4.z, d4.w);
      *(uint4*)(dst + ck * 16) = s0;
      *(uint4*)(dst + ck * 16 + 8) = s1;
    }
  }
  __syncthreads();

  // ---- MFMA ----
  const int wv = t >> 6;
  const int lane = t & 63;
  const int lrow = lane & 15;  // A-row (pixel) / B-col (n)
  const int lhi = lane >> 4;   // k sub-block
  const int pixrow = pbase + (wv << 4) + lrow;

  U8 afr[4];
#pragma unroll
  for (int kt = 0; kt < 4; ++kt) {
    const float* ax = x + (size_t)pixrow * 128 + (kt << 5) + (lhi << 3);
    const float4 xa = *(const float4*)ax;
    const float4 xb4 = *(const float4*)(ax + 4);
    afr[kt].u[0] = pkbf(xa.x, xa.y);   afr[kt].u[1] = pkbf(xa.z, xa.w);
    afr[kt].u[2] = pkbf(xb4.x, xb4.y); afr[kt].u[3] = pkbf(xb4.z, xb4.w);
  }

  f32x4 acc[7];
#pragma unroll
  for (int nt = 0; nt < 7; ++nt) {
    const float bv = bias_lds[(nt << 4) + lrow];
    f32x4 a4 = {bv, bv, bv, bv};
#pragma unroll
    for (int kt = 0; kt < 4; ++kt) {
      U8 bfr;
      const uint4 bw =
          *(const uint4*)(wt + ((nt << 4) + lrow) * 68 + (kt << 4) + (lhi << 2));
      bfr.u[0] = bw.x; bfr.u[1] = bw.y; bfr.u[2] = bw.z; bfr.u[3] = bw.w;
      a4 = __builtin_amdgcn_mfma_f32_16x16x32_bf16(afr[kt].v, bfr.v, a4, 0, 0, 0);
    }
    acc[nt] = a4;
  }

  // ---- epilogue: fp16 transpose via LDS (reuse wt), then coalesced copy ----
  __syncthreads();  // all waves done reading wt
  {
    ushort* tl = (ushort*)wt;  // 64 px x 128 ushorts = 16 KB
    const int plb = (wv << 4) + (lhi << 2);
#pragma unroll
    for (int nt = 0; nt < 7; ++nt) {
      const int n = (nt << 4) + lrow;
      if (n < 108) {
        int ridx;
        if (n < 72) {
          const int gg = n / 18;
          ridx = (gg << 5) + (n - gg * 18);
        } else {
          const int m = n - 72;
          const int gg = m / 9;
          ridx = (gg << 5) + 18 + (m - gg * 9);
        }
        tl[(plb + 0) * 128 + ridx] = f2h(acc[nt].x);
        tl[(plb + 1) * 128 + ridx] = f2h(acc[nt].y);
        tl[(plb + 2) * 128 + ridx] = f2h(acc[nt].z);
        tl[(plb + 3) * 128 + ridx] = f2h(acc[nt].w);
      }
    }
  }
  __syncthreads();
  {
    const uint* src = (const uint*)wt;
    uint4* dst = (uint4*)(ws16 + (size_t)pbase * 128);
#pragma unroll
    for (int i = 0; i < 4; ++i) {
      const int idx = (i << 8) + t;  // 1024 uint4 = 16 KB
      const uint4 v = *(const uint4*)(src + idx * 4);
      dst[idx] = v;
    }
  }
}

// ---------------- Kernel B: bilinear gather from bf16 planar ---------------
// R6-proven gather structure: block 256 = 64 (pixel,group) pairs x 4
// chunk-lanes; g = blockIdx&3. ws record read as 4 vector loads; all 27
// offsets/logits register-resident before the 9-point loop -> no per-point
// scalar-load dependency; compiler pipelines the gathers (full unroll).
__global__ __launch_bounds__(256) void dcn_samp(
    const ushort* __restrict__ x16, const ushort* __restrict__ ws16,
    float* __restrict__ out) {
  const int g = blockIdx.x & 3;
  const int pg = threadIdx.x >> 2;   // 0..63: pixel within block
  const int sub = threadIdx.x & 3;   // 16B chunk within the group slice
  const int q = ((blockIdx.x >> 2) << 6) | pg;
  const int b = q >> 14;
  const int h = (q >> 7) & 127;
  const int w = q & 127;
  const ushort* xg = x16 + (((size_t)((g << 2) | b)) << 19) + (sub << 3);

  // ---- one 56B record read: 18 offsets + 9 logits (fp16) ----
  const ushort* wsrec = ws16 + (size_t)q * 128 + (g << 5);
  const uint4 r0 = *(const uint4*)(wsrec);
  const uint4 r1 = *(const uint4*)(wsrec + 8);
  const uint4 r2 = *(const uint4*)(wsrec + 16);
  const uint2 r3 = *(const uint2*)(wsrec + 24);
  // rr[i] = ushorts {2i, 2i+1}; indices are compile-time after unroll
  const uint rr0 = r0.x, rr1 = r0.y, rr2 = r0.z, rr3 = r0.w;
  const uint rr4 = r1.x, rr5 = r1.y, rr6 = r1.z, rr7 = r1.w;
  const uint rr8 = r2.x, rr9 = r2.y, rr10 = r2.z, rr11 = r2.w;
  const uint rr12 = r3.x, rr13 = r3.y;

  float offx9[9], offy9[9], mk9[9];
  {
    const uint rra[14] = {rr0, rr1, rr2,  rr3,  rr4,  rr5,  rr6,
                          rr7, rr8, rr9, rr10, rr11, rr12, rr13};
#pragma unroll
    for (int p = 0; p < 9; ++p) {
      offx9[p] = h2f_lo(rra[p]);   // ushort 2p
      offy9[p] = h2f_hi(rra[p]);   // ushort 2p+1
      const int li = 18 + p;       // logit ushort index
      mk9[p] = (li & 1) ? h2f_hi(rra[li >> 1]) : h2f_lo(rra[li >> 1]);
    }
    float mx = mk9[0];
#pragma unroll
    for (int p = 1; p < 9; ++p) mx = fmaxf(mx, mk9[p]);
    float s = 0.f;
#pragma unroll
    for (int p = 0; p < 9; ++p) {
      mk9[p] = __expf(mk9[p] - mx);
      s += mk9[p];
    }
    const float sinv = 1.0f / s;
#pragma unroll
    for (int p = 0; p < 9; ++p) mk9[p] *= sinv;
  }

  float a0 = 0.f, a1 = 0.f, a2 = 0.f, a3 = 0.f;
  float a4 = 0.f, a5 = 0.f, a6 = 0.f, a7 = 0.f;

#pragma unroll
  for (int p = 0; p < 9; ++p) {
    const float mk = mk9[p];
    const float px = (float)(w + p / 3) + offx9[p];
    const float py = (float)(h + p % 3) + offy9[p];
    const float fx = floorf(px), fy = floorf(py);
    const float tx = px - fx, ty = py - fy;
    const int x0 = (int)fx - 1, y0 = (int)fy - 1;
    const int x1 = x0 + 1, y1 = y0 + 1;
    const float ax0 = ((unsigned)x0 < 128u) ? (1.f - tx) : 0.f;
    const float ax1 = ((unsigned)x1 < 128u) ? tx : 0.f;
    const float ay0 = ((unsigned)y0 < 128u) ? (mk * (1.f - ty)) : 0.f;
    const float ay1 = ((unsigned)y1 < 128u) ? (mk * ty) : 0.f;
    const float w00 = ax0 * ay0, w10 = ax1 * ay0;
    const float w01 = ax0 * ay1, w11 = ax1 * ay1;
    const int cx0 = min(max(x0, 0), 127), cy0 = min(max(y0, 0), 127);
    const int cx1 = min(max(x1, 0), 127), cy1 = min(max(y1, 0), 127);
    const int o00 = ((cy0 << 7) | cx0) << 5;
    const int o10 = ((cy0 << 7) | cx1) << 5;
    const int o01 = ((cy1 << 7) | cx0) << 5;
    const int o11 = ((cy1 << 7) | cx1) << 5;
    const uint4 d00 = *(const uint4*)(xg + o00);
    const uint4 d10 = *(const uint4*)(xg + o10);
    const uint4 d01 = *(const uint4*)(xg + o01);
    const uint4 d11 = *(const uint4*)(xg + o11);
    a0 = fmaf(w00, bflo(d00.x), fmaf(w10, bflo(d10.x),
         fmaf(w01, bflo(d01.x), fmaf(w11, bflo(d11.x), a0))));
    a1 = fmaf(w00, bfhi(d00.x), fmaf(w10, bfhi(d10.x),
         fmaf(w01, bfhi(d01.x), fmaf(w11, bfhi(d11.x), a1))));
    a2 = fmaf(w00, bflo(d00.y), fmaf(w10, bflo(d10.y),
         fmaf(w01, bflo(d01.y), fmaf(w11, bflo(d11.y), a2))));
    a3 = fmaf(w00, bfhi(d00.y), fmaf(w10, bfhi(d10.y),
         fmaf(w01, bfhi(d01.y), fmaf(w11, bfhi(d11.y), a3))));
    a4 = fmaf(w00, bflo(d00.z), fmaf(w10, bflo(d10.z),
         fmaf(w01, bflo(d01.z), fmaf(w11, bflo(d11.z), a4))));
    a5 = fmaf(w00, bfhi(d00.z), fmaf(w10, bfhi(d10.z),
         fmaf(w01, bfhi(d01.z), fmaf(w11, bfhi(d11.z), a5))));
    a6 = fmaf(w00, bflo(d00.w), fmaf(w10, bflo(d10.w),
         fmaf(w01, bflo(d01.w), fmaf(w11, bflo(d11.w), a6))));
    a7 = fmaf(w00, bfhi(d00.w), fmaf(w10, bfhi(d10.w),
         fmaf(w01, bfhi(d01.w), fmaf(w11, bfhi(d11.w), a7))));
  }

  float* op = out + (size_t)q * 128 + (g << 5) + (sub << 3);
  float4 oa, ob;
  oa.x = a0; oa.y = a1; oa.z = a2; oa.w = a3;
  ob.x = a4; ob.y = a5; ob.z = a6; ob.w = a7;
  *(float4*)op = oa;
  *(float4*)(op + 4) = ob;
}

// ---------------- Tier-2 fallback: legacy VALU lin (with softmax) ----------
__global__ __launch_bounds__(256) void dcn_lin(
    const float* __restrict__ x, const float* __restrict__ Woff,
    const float* __restrict__ boff, const float* __restrict__ Wmask,
    const float* __restrict__ bmask, float* __restrict__ ws) {
  const int jg = blockIdx.x >> 8;
  const int pix = ((blockIdx.x & 255) << 8) | threadIdx.x;
  const float* W;
  const float* bias;
  int ldw, obase;
  if (jg == 0) {
    W = Woff; bias = boff; ldw = 72; obase = 0;
  } else if (jg == 1) {
    W = Woff + 36; bias = boff + 36; ldw = 72; obase = 36;
  } else {
    W = Wmask; bias = bmask; ldw = 36; obase = 72;
  }
  float acc[36];
#pragma unroll
  for (int j = 0; j < 36; ++j) acc[j] = bias[j];
  const float* xp = x + (size_t)pix * 128;
  for (int c0 = 0; c0 < 128; c0 += 8) {
    float xr[8];
    *(float4*)(xr) = *(const float4*)(xp + c0);
    *(float4*)(xr + 4) = *(const float4*)(xp + c0 + 4);
#pragma unroll
    for (int cc = 0; cc < 8; ++cc) {
      const float xc = xr[cc];
      const float* wr = W + (size_t)(c0 + cc) * ldw;
#pragma unroll
      for (int j = 0; j < 36; ++j) acc[j] = fmaf(xc, wr[j], acc[j]);
    }
  }
  if (jg == 2) {
#pragma unroll
    for (int g = 0; g < 4; ++g) {
      float mx = acc[g * 9];
#pragma unroll
      for (int p = 1; p < 9; ++p) mx = fmaxf(mx, acc[g * 9 + p]);
      float s = 0.f;
#pragma unroll
      for (int p = 0; p < 9; ++p) {
        acc[g * 9 + p] = __expf(acc[g * 9 + p] - mx);
        s += acc[g * 9 + p];
      }
      const float sinv = 1.0f / s;
#pragma unroll
      for (int p = 0; p < 9; ++p) acc[g * 9 + p] *= sinv;
    }
  }
#pragma unroll
  for (int j = 0; j < 36; ++j) ws[(size_t)(obase + j) * NPIX + pix] = acc[j];
}

// ---------------- Tier-2 fallback: fp32 gather (R2-proven) ----------------
__global__ __launch_bounds__(256) void dcn_samp_f32(
    const float* __restrict__ x, const float* __restrict__ ws,
    float* __restrict__ out) {
  const int q = (blockIdx.x << 4) | (threadIdx.x >> 4);
  const int sub = threadIdx.x & 15;
  const int c = sub << 3;
  const int g = sub >> 2;
  const int b = q >> 14;
  const int h = (q >> 7) & 127;
  const int w = q & 127;
  const float* xb = x + ((size_t)b << 21) + c;
  const float* wsq = ws + q;
  float a0 = 0.f, a1 = 0.f, a2 = 0.f, a3 = 0.f;
  float a4 = 0.f, a5 = 0.f, a6 = 0.f, a7 = 0.f;
#pragma unroll
  for (int p = 0; p < 9; ++p) {
    const float offx = wsq[(size_t)(g * 18 + p * 2) * NPIX];
    const float offy = wsq[(size_t)(g * 18 + p * 2 + 1) * NPIX];
    const float mk = wsq[(size_t)(72 + g * 9 + p) * NPIX];
    const float px = (float)(w + p / 3) + offx;
    const float py = (float)(h + p % 3) + offy;
    const float fx = floorf(px), fy = floorf(py);
    const float tx = px - fx, ty = py - fy;
    const int x0 = (int)fx - 1, y0 = (int)fy - 1;
    const int x1 = x0 + 1, y1 = y0 + 1;
    const float ax0 = ((unsigned)x0 < 128u) ? (1.f - tx) : 0.f;
    const float ax1 = ((unsigned)x1 < 128u) ? tx : 0.f;
    const float ay0 = ((unsigned)y0 < 128u) ? (mk * (1.f - ty)) : 0.f;
    const float ay1 = ((unsigned)y1 < 128u) ? (mk * ty) : 0.f;
    const float w00 = ax0 * ay0, w10 = ax1 * ay0;
    const float w01 = ax0 * ay1, w11 = ax1 * ay1;
    const int cx0 = min(max(x0, 0), 127), cy0 = min(max(y0, 0), 127);
    const int cx1 = min(max(x1, 0), 127), cy1 = min(max(y1, 0), 127);
    const int o00 = (cy0 << 14) | (cx0 << 7), o10 = (cy0 << 14) | (cx1 << 7);
    const int o01 = (cy1 << 14) | (cx0 << 7), o11 = (cy1 << 14) | (cx1 << 7);
    const float4 v00a = *(const float4*)(xb + o00);
    const float4 v00b = *(const float4*)(xb + o00 + 4);
    const float4 v10a = *(const float4*)(xb + o10);
    const float4 v10b = *(const float4*)(xb + o10 + 4);
    const float4 v01a = *(const float4*)(xb + o01);
    const float4 v01b = *(const float4*)(xb + o01 + 4);
    const float4 v11a = *(const float4*)(xb + o11);
    const float4 v11b = *(const float4*)(xb + o11 + 4);
    a0 = fmaf(w00, v00a.x, fmaf(w10, v10a.x, fmaf(w01, v01a.x, fmaf(w11, v11a.x, a0))));
    a1 = fmaf(w00, v00a.y, fmaf(w10, v10a.y, fmaf(w01, v01a.y, fmaf(w11, v11a.y, a1))));
    a2 = fmaf(w00, v00a.z, fmaf(w10, v10a.z, fmaf(w01, v01a.z, fmaf(w11, v11a.z, a2))));
    a3 = fmaf(w00, v00a.w, fmaf(w10, v10a.w, fmaf(w01, v01a.w, fmaf(w11, v11a.w, a3))));
    a4 = fmaf(w00, v00b.x, fmaf(w10, v10b.x, fmaf(w01, v01b.x, fmaf(w11, v11b.x, a4))));
    a5 = fmaf(w00, v00b.y, fmaf(w10, v10b.y, fmaf(w01, v01b.y, fmaf(w11, v11b.y, a5))));
    a6 = fmaf(w00, v00b.z, fmaf(w10, v10b.z, fmaf(w01, v01b.z, fmaf(w11, v11b.z, a6))));
    a7 = fmaf(w00, v00b.w, fmaf(w10, v10b.w, fmaf(w01, v01b.w, fmaf(w11, v11b.w, a7))));
  }
  float4 oa, ob;
  oa.x = a0; oa.y = a1; oa.z = a2; oa.w = a3;
  ob.x = a4; ob.y = a5; ob.z = a6; ob.w = a7;
  float* op = out + (size_t)q * 128 + c;
  *(float4*)op = oa;
  *(float4*)(op + 4) = ob;
}

// ---------------- Tier-3 fallback: fully fused ----------------
__global__ __launch_bounds__(128) void dcn_fused(
    const float* __restrict__ x, const float* __restrict__ Woff,
    const float* __restrict__ boff, const float* __restrict__ Wmask,
    const float* __restrict__ bmask, float* __restrict__ out) {
  __shared__ float xs[128];
  __shared__ float res[108];
  __shared__ float msk[36];
  const int q = blockIdx.x;
  const int t = threadIdx.x;
  const int b = q >> 14, h = (q >> 7) & 127, w = q & 127;
  xs[t] = x[(size_t)q * 128 + t];
  __syncthreads();
  if (t < 108) {
    float a;
    const float* W;
    int ld;
    if (t < 72) {
      a = boff[t]; W = Woff + t; ld = 72;
    } else {
      a = bmask[t - 72]; W = Wmask + (t - 72); ld = 36;
    }
    for (int cc = 0; cc < 128; ++cc) a = fmaf(xs[cc], W[(size_t)cc * ld], a);
    res[t] = a;
  }
  __syncthreads();
  if (t < 4) {
    float mx = -1e30f;
    for (int p = 0; p < 9; ++p) mx = fmaxf(mx, res[72 + t * 9 + p]);
    float s = 0.f;
    float e[9];
    for (int p = 0; p < 9; ++p) {
      e[p] = __expf(res[72 + t * 9 + p] - mx);
      s += e[p];
    }
    for (int p = 0; p < 9; ++p) msk[t * 9 + p] = e[p] / s;
  }
  __syncthreads();
  const int g = t >> 5;
  const float* xb = x + ((size_t)b << 21) + t;
  float acc = 0.f;
#pragma unroll
  for (int p = 0; p < 9; ++p) {
    const float offx = res[g * 18 + p * 2];
    const float offy = res[g * 18 + p * 2 + 1];
    const float px = (float)(w + p / 3) + offx;
    const float py = (float)(h + p % 3) + offy;
    const float fx = floorf(px), fy = floorf(py);
    const float tx = px - fx, ty = py - fy;
    const int x0 = (int)fx - 1, y0 = (int)fy - 1;
    float sv = 0.f;
#define CORNER1(XI, YI, WT)                                       \
  if ((unsigned)(XI) < 128u && (unsigned)(YI) < 128u)             \
    sv = fmaf((WT), xb[((size_t)(YI) << 14) + ((size_t)(XI) << 7)], sv);
    CORNER1(x0, y0, (1.f - tx) * (1.f - ty))
    CORNER1(x0 + 1, y0, tx * (1.f - ty))
    CORNER1(x0, y0 + 1, (1.f - tx) * ty)
    CORNER1(x0 + 1, y0 + 1, tx * ty)
#undef CORNER1
    acc = fmaf(msk[g * 9 + p], sv, acc);
  }
  out[(size_t)q * 128 + t] = acc;
}

extern "C" void kernel_launch(void* const* d_in, const int* in_sizes, int n_in,
                              void* d_out, int out_size, void* d_ws,
                              size_t ws_size, hipStream_t stream) {
  const float* x = (const float*)d_in[0];
  const float* Woff = (const float*)d_in[1];
  const float* boff = (const float*)d_in[2];
  const float* Wmask = (const float*)d_in[3];
  const float* bmask = (const float*)d_in[4];
  float* out = (float*)d_out;
  const size_t need_ws = (size_t)NPIX * 108 * sizeof(float);
  const size_t need_full = (size_t)NPIX * (128 + 128) * sizeof(ushort);
  if (ws_size >= need_full) {
    ushort* x16 = (ushort*)d_ws;                        // 16 MB
    ushort* ws16 = (ushort*)d_ws + (size_t)NPIX * 128;  // 16.8 MB (AoS)
    dcn_lin_mfma<<<1024, 256, 0, stream>>>(x, Woff, boff, Wmask, bmask, ws16,
                                           x16);
    dcn_samp<<<4096, 256, 0, stream>>>(x16, ws16, out);
  } else if (ws_size >= need_ws) {
    float* ws = (float*)d_ws;
    dcn_lin<<<768, 256, 0, stream>>>(x, Woff, boff, Wmask, bmask, ws);
    dcn_samp_f32<<<4096, 256, 0, stream>>>(x, ws, out);
  } else {
    dcn_fused<<<NPIX, 128, 0, stream>>>(x, Woff, boff, Wmask, bmask, out);
  }
}